// Round 1
// baseline (13075.092 us; speedup 1.0000x reference)
//
#include <hip/hip_runtime.h>
#include <hip/hip_bf16.h>

// Problem sizes
#define Bb 128
#define Tt 1024
#define Dd 256
#define Hh 512
#define G4 2048
#define Oo 256

#define NWG 64      // 4 batch-groups x 16 j-groups
#define BLOCK 256   // 4 waves

typedef __attribute__((ext_vector_type(8)))  short  short8;
typedef __attribute__((ext_vector_type(4)))  short  short4v;
typedef __attribute__((ext_vector_type(4)))  float  f32x4;
typedef __attribute__((ext_vector_type(16))) float  f32x16;

// ws layout: [flags: 64 slots * 16 ints = 4KB][hbuf: 2*128*512 bf16 = 256KB]
#define FLAGS_OFF 0
#define HBUF_OFF  4096
#define WS_ZERO_BYTES (4096 + 2*Bb*Hh*2)

__device__ __forceinline__ short f2bf(float f) {
  __hip_bfloat16 h = __float2bfloat16(f);
  return *reinterpret_cast<short*>(&h);
}

__global__ __launch_bounds__(BLOCK, 1) void lstm_seq(
    const float* __restrict__ X, const float* __restrict__ Wi,
    const float* __restrict__ Wh, const float* __restrict__ bias,
    __hip_bfloat16* hbuf, int* flags)
{
  // Shared A-tile for this wg's 32 batch rows (shared by all 4 waves).
  __shared__ char sH[32 * 1024];   // 32 rows x 512 bf16 (h part), XOR-swizzled
  __shared__ char sX[32 * 512];    // 32 rows x 256 bf16 (x part), XOR-swizzled
  __shared__ float sY[4][32][32];  // per-wave y staging (f32)

  const int tid   = threadIdx.x;
  const int w     = tid >> 6;     // wave 0..3
  const int lane  = tid & 63;
  const int khalf = lane >> 5;    // 0/1
  const int n     = lane & 31;    // MFMA row/col lane index

  const int gb = blockIdx.x >> 4; // batch group 0..3  (rows gb*32 .. +32)
  const int gj = blockIdx.x & 15; // j group 0..15

  // Gate-column handled by this lane (B-fragment / bias / output col):
  // wave w owns j-sub [gj*32 + w*8, +8) across all 4 gates, arranged
  // n = gate*8 + jj  (gate: 0=i,1=f,2=g,3=o)
  const int gate = n >> 3;
  const int jj   = n & 7;
  const int colg = gate * Hh + gj * 32 + w * 8 + jj;

  // ---- Load weight B-fragments into registers (persistent, one-time).
  // wfrag[kk]: k = kk*16 + khalf*8 + i ; k<512 -> Wh, else Wi (x part)
  short8 wfrag[48];
#pragma unroll
  for (int kk = 0; kk < 48; ++kk) {
    short8 f;
#pragma unroll
    for (int i = 0; i < 8; ++i) {
      int k = kk * 16 + khalf * 8 + i;
      float v = (k < Hh) ? Wh[(size_t)k * G4 + colg]
                         : Wi[(size_t)(k - Hh) * G4 + colg];
      f[i] = f2bf(v);
    }
    wfrag[kk] = f;
  }
  const float bv = bias[colg];

  // Epilogue lane mapping: (j, bb) with 4 batch rows per lane (bl = bb + 8m)
  const int j  = lane & 7;
  const int bb = (lane >> 3) & 7;
  float cpr[4] = {0.f, 0.f, 0.f, 0.f};

  int* myflag = flags + blockIdx.x * 16;
  const int flgbase = gb * 16;
  const int arow = n;
  const int swz  = (arow & 7) << 4;

  for (int s = 1; s <= Tt; ++s) {
    const __hip_bfloat16* hread  = hbuf + ((size_t)((s - 1) & 1)) * Bb * Hh;
    __hip_bfloat16*       hwrite = hbuf + ((size_t)(s & 1)) * Bb * Hh;

    // ---- stage x_t rows (read-only: stale L2 is fine, do before fence)
    // wave w stages rows w*8 .. w*8+7 ; one row per iter: 64 lanes x 4 f32
#pragma unroll
    for (int it = 0; it < 8; ++it) {
      int r  = w * 8 + it;
      int b_ = gb * 32 + r;
      f32x4 xv = *reinterpret_cast<const f32x4*>(
          X + ((size_t)b_ * Tt + (s - 1)) * Dd + lane * 4);
      short4v xb;
      xb[0] = f2bf(xv[0]); xb[1] = f2bf(xv[1]);
      xb[2] = f2bf(xv[2]); xb[3] = f2bf(xv[3]);
      *reinterpret_cast<short4v*>(sX + r * 512 + ((lane * 8) ^ ((r & 7) << 4))) = xb;
    }

    // ---- wait for h(s-1) producers of this batch group (16 wgs)
    if (s > 1 && w == 0) {
      const int tgt = s - 1;
      int* fp = flags + (flgbase + (lane & 15)) * 16;
      int v;
      do {
        v = __hip_atomic_load(fp, __ATOMIC_RELAXED, __HIP_MEMORY_SCOPE_AGENT);
      } while (!__all(v >= tgt));
    }
    __syncthreads();
    if (s > 1) __threadfence();  // acquire: invalidate L1/L2 before h reads

    // ---- stage h(s-1) rows (wave w: rows w*8..+7; 64 lanes x 16B = 1 row)
#pragma unroll
    for (int it = 0; it < 8; ++it) {
      int r  = w * 8 + it;
      int b_ = gb * 32 + r;
      short8 hv = *reinterpret_cast<const short8*>(hread + (size_t)b_ * Hh + lane * 8);
      *reinterpret_cast<short8*>(sH + r * 1024 + ((lane * 16) ^ ((r & 7) << 4))) = hv;
    }
    __syncthreads();

    // ---- MFMA: 48 k-steps of 32x32x16 (h: 32 steps, x: 16 steps)
    f32x16 acc;
#pragma unroll
    for (int m = 0; m < 16; ++m) acc[m] = bv;
#pragma unroll
    for (int kk = 0; kk < 32; ++kk) {
      short8 a = *reinterpret_cast<const short8*>(
          sH + arow * 1024 + ((((kk * 2 + khalf) * 16)) ^ swz));
      acc = __builtin_amdgcn_mfma_f32_32x32x16_bf16(a, wfrag[kk], acc, 0, 0, 0);
    }
#pragma unroll
    for (int kk = 0; kk < 16; ++kk) {
      short8 a = *reinterpret_cast<const short8*>(
          sX + arow * 512 + ((((kk * 2 + khalf) * 16)) ^ swz));
      acc = __builtin_amdgcn_mfma_f32_32x32x16_bf16(a, wfrag[32 + kk], acc, 0, 0, 0);
    }

    // ---- epilogue: stage y (C/D map: col=n, row=(m&3)+8*(m>>2)+4*khalf)
    float* yb = &sY[w][0][0];
#pragma unroll
    for (int m = 0; m < 16; ++m) {
      int row = (m & 3) + ((m >> 2) << 3) + (khalf << 2);
      yb[row * 32 + n] = acc[m];
    }
    // gates (ds in-order within wave; compiler inserts lgkmcnt)
#pragma unroll
    for (int m = 0; m < 4; ++m) {
      int bl = bb + (m << 3);
      float yi = yb[bl * 32 + j];
      float yf = yb[bl * 32 + 8 + j];
      float yg = yb[bl * 32 + 16 + j];
      float yo = yb[bl * 32 + 24 + j];
      float ig = 1.f / (1.f + __expf(-yi));
      float fg = 1.f / (1.f + __expf(-yf));
      float gg = tanhf(yg);
      float og = 1.f / (1.f + __expf(-yo));
      float c  = fg * cpr[m] + ig * gg;
      cpr[m]   = c;
      float hh = og * tanhf(c);
      hwrite[(size_t)(gb * 32 + bl) * Hh + gj * 32 + w * 8 + j] = __float2bfloat16(hh);
    }
    __syncthreads();  // all h stores drained (vmcnt0 per wave before barrier)
    if (tid == 0) {
      __hip_atomic_store(myflag, s, __ATOMIC_RELEASE, __HIP_MEMORY_SCOPE_AGENT);
    }
  }
}

__global__ void out_dense(const __hip_bfloat16* __restrict__ hT,
                          const float* __restrict__ Wd,
                          const float* __restrict__ bd,
                          float* __restrict__ out)
{
  __shared__ float hrow[Hh];
  int b = blockIdx.x;
  int o = threadIdx.x;
  for (int k = o; k < Hh; k += Oo)
    hrow[k] = __bfloat162float(hT[(size_t)b * Hh + k]);
  __syncthreads();
  float acc = bd[o];
  for (int k = 0; k < Hh; ++k)
    acc = fmaf(hrow[k], Wd[(size_t)k * Oo + o], acc);
  out[(size_t)b * Oo + o] = acc;
}

extern "C" void kernel_launch(void* const* d_in, const int* in_sizes, int n_in,
                              void* d_out, int out_size, void* d_ws, size_t ws_size,
                              hipStream_t stream) {
  (void)in_sizes; (void)n_in; (void)out_size; (void)ws_size;
  const float* X  = (const float*)d_in[0];
  const float* Wi = (const float*)d_in[1];
  const float* Wh = (const float*)d_in[2];
  const float* b  = (const float*)d_in[3];
  const float* Wd = (const float*)d_in[4];
  const float* bd = (const float*)d_in[5];
  float* out = (float*)d_out;

  char* ws = (char*)d_ws;
  int* flags = (int*)(ws + FLAGS_OFF);
  __hip_bfloat16* hbuf = (__hip_bfloat16*)(ws + HBUF_OFF);

  // zero flags + h(0) every launch (graph-replay deterministic)
  hipMemsetAsync(d_ws, 0, WS_ZERO_BYTES, stream);
  lstm_seq<<<NWG, BLOCK, 0, stream>>>(X, Wi, Wh, b, hbuf, flags);
  out_dense<<<Bb, Oo, 0, stream>>>(hbuf, Wd, bd, out);
}

// Round 2
// 7943.280 us; speedup vs baseline: 1.6461x; 1.6461x over previous
//
#include <hip/hip_runtime.h>
#include <hip/hip_bf16.h>

// Problem sizes
#define Bb 128
#define Tt 1024
#define Dd 256
#define Hh 512
#define G4 2048
#define Oo 256

#define NWG 64      // 4 batch-groups x 16 j-groups
#define BLOCK 256   // 4 waves

typedef __attribute__((ext_vector_type(8)))  short  short8;
typedef __attribute__((ext_vector_type(4)))  short  short4v;
typedef __attribute__((ext_vector_type(4)))  float  f32x4;
typedef __attribute__((ext_vector_type(16))) float  f32x16;
typedef unsigned long long u64;

// ws layout: [flags: 64 slots * 16 ints = 4KB][hbuf: 2*128*512 bf16 = 256KB]
#define FLAGS_OFF 0
#define HBUF_OFF  4096
#define WS_ZERO_BYTES (4096 + 2*Bb*Hh*2)

__device__ __forceinline__ short f2bf(float f) {
  __hip_bfloat16 h = __float2bfloat16(f);
  return *reinterpret_cast<short*>(&h);
}
__device__ __forceinline__ float bf2f(unsigned short u) {
  union { unsigned int i; float f; } c; c.i = ((unsigned)u) << 16; return c.f;
}

__global__ __launch_bounds__(BLOCK, 1) void lstm_seq(
    const float* __restrict__ X, const float* __restrict__ Wi,
    const float* __restrict__ Wh, const float* __restrict__ bias,
    __hip_bfloat16* hbuf, int* flags)
{
  __shared__ char sH[32 * 1024];          // 32 rows x 512 bf16 (h), XOR-swizzled
  __shared__ char sX[32 * 512];           // 32 rows x 256 bf16 (x), XOR-swizzled
  __shared__ float sY[4][32][32];         // per-wave y staging (f32)
  __shared__ unsigned short hstage[32][32]; // h bf16 bits, for packed 8B stores

  const int tid   = threadIdx.x;
  const int w     = tid >> 6;     // wave 0..3
  const int lane  = tid & 63;
  const int khalf = lane >> 5;    // 0/1
  const int n     = lane & 31;    // MFMA row/col lane index

  const int gb = blockIdx.x >> 4; // batch group 0..3  (rows gb*32 .. +32)
  const int gj = blockIdx.x & 15; // j group 0..15

  // Gate-column handled by this lane: n = gate*8 + jj (gate: 0=i,1=f,2=g,3=o)
  const int gate = n >> 3;
  const int jj   = n & 7;
  const int colg = gate * Hh + gj * 32 + w * 8 + jj;

  // ---- Load weight B-fragments into registers (persistent, one-time).
  short8 wfrag[48];
#pragma unroll
  for (int kk = 0; kk < 48; ++kk) {
    short8 f;
#pragma unroll
    for (int i = 0; i < 8; ++i) {
      int k = kk * 16 + khalf * 8 + i;
      float v = (k < Hh) ? Wh[(size_t)k * G4 + colg]
                         : Wi[(size_t)(k - Hh) * G4 + colg];
      f[i] = f2bf(v);
    }
    wfrag[kk] = f;
  }
  const float bv = bias[colg];

  // Epilogue lane mapping: (j, bb) with 4 batch rows per lane (bl = bb + 8m)
  const int j  = lane & 7;
  const int bb = (lane >> 3) & 7;
  float cpr[4] = {0.f, 0.f, 0.f, 0.f};

  int* myflag = flags + blockIdx.x * 16;
  const int flgbase = gb * 16;
  const int arow = n;
  const int swz  = (arow & 7) << 4;

  // pack-store lane mapping
  const int prow = tid >> 3;       // 0..31
  const int pcq  = tid & 7;        // 8B chunk (4 bf16 cols)

  for (int s = 1; s <= Tt; ++s) {
    const __hip_bfloat16* hread  = hbuf + ((size_t)((s - 1) & 1)) * Bb * Hh;
    __hip_bfloat16*       hwrite = hbuf + ((size_t)(s & 1)) * Bb * Hh;

    // ---- stage x_t rows (read-only input; normal cached loads)
#pragma unroll
    for (int it = 0; it < 8; ++it) {
      int r  = w * 8 + it;
      int b_ = gb * 32 + r;
      f32x4 xv = *reinterpret_cast<const f32x4*>(
          X + ((size_t)b_ * Tt + (s - 1)) * Dd + lane * 4);
      short4v xb;
      xb[0] = f2bf(xv[0]); xb[1] = f2bf(xv[1]);
      xb[2] = f2bf(xv[2]); xb[3] = f2bf(xv[3]);
      *reinterpret_cast<short4v*>(sX + r * 512 + ((lane * 8) ^ ((r & 7) << 4))) = xb;
    }

    // ---- wait for h(s-1) producers of this batch group (16 wgs)
    if (s > 1 && w == 0) {
      const int tgt = s - 1;
      int* fp = flags + (flgbase + (lane & 15)) * 16;
      int v;
      do {
        v = __hip_atomic_load(fp, __ATOMIC_RELAXED, __HIP_MEMORY_SCOPE_AGENT);
      } while (!__all(v >= tgt));
    }
    __syncthreads();
    // no __threadfence: h loads below bypass L2 (agent-scope) and L3 is the
    // coherence point where producers' write-through stores already landed.

    // ---- stage h(s-1) rows via L2-bypassing 8B atomic loads
#pragma unroll
    for (int it = 0; it < 8; ++it) {
      int r  = w * 8 + it;
      int b_ = gb * 32 + r;
      const u64* src = reinterpret_cast<const u64*>(hread + (size_t)b_ * Hh);
      u64 lo = __hip_atomic_load(src + lane * 2,     __ATOMIC_RELAXED, __HIP_MEMORY_SCOPE_AGENT);
      u64 hi = __hip_atomic_load(src + lane * 2 + 1, __ATOMIC_RELAXED, __HIP_MEMORY_SCOPE_AGENT);
      union { u64 u[2]; short8 s8; } cv;
      cv.u[0] = lo; cv.u[1] = hi;
      *reinterpret_cast<short8*>(sH + r * 1024 + ((lane * 16) ^ ((r & 7) << 4))) = cv.s8;
    }
    __syncthreads();

    // ---- MFMA: 48 k-steps of 32x32x16 (h: 32 steps, x: 16 steps)
    f32x16 acc;
#pragma unroll
    for (int m = 0; m < 16; ++m) acc[m] = bv;
#pragma unroll
    for (int kk = 0; kk < 32; ++kk) {
      short8 a = *reinterpret_cast<const short8*>(
          sH + arow * 1024 + ((((kk * 2 + khalf) * 16)) ^ swz));
      acc = __builtin_amdgcn_mfma_f32_32x32x16_bf16(a, wfrag[kk], acc, 0, 0, 0);
    }
#pragma unroll
    for (int kk = 0; kk < 16; ++kk) {
      short8 a = *reinterpret_cast<const short8*>(
          sX + arow * 512 + ((((kk * 2 + khalf) * 16)) ^ swz));
      acc = __builtin_amdgcn_mfma_f32_32x32x16_bf16(a, wfrag[32 + kk], acc, 0, 0, 0);
    }

    // ---- epilogue: stage y (C/D map: col=n, row=(m&3)+8*(m>>2)+4*khalf)
    float* yb = &sY[w][0][0];
#pragma unroll
    for (int m = 0; m < 16; ++m) {
      int row = (m & 3) + ((m >> 2) << 3) + (khalf << 2);
      yb[row * 32 + n] = acc[m];
    }
#pragma unroll
    for (int m = 0; m < 4; ++m) {
      int bl = bb + (m << 3);
      float yi = yb[bl * 32 + j];
      float yf = yb[bl * 32 + 8 + j];
      float yg = yb[bl * 32 + 16 + j];
      float yo = yb[bl * 32 + 24 + j];
      float ig = 1.f / (1.f + __expf(-yi));
      float fg = 1.f / (1.f + __expf(-yf));
      float gg = tanhf(yg);
      float og = 1.f / (1.f + __expf(-yo));
      float c  = fg * cpr[m] + ig * gg;
      cpr[m]   = c;
      float hh = og * tanhf(c);
      __hip_bfloat16 hb = __float2bfloat16(hh);
      hstage[bl][w * 8 + j] = *reinterpret_cast<unsigned short*>(&hb);
    }
    __syncthreads();

    // ---- packed 8B write-through h stores (bypass L2, land at L3)
    {
      u64 pk = *reinterpret_cast<const u64*>(&hstage[prow][pcq * 4]);
      u64* dst = reinterpret_cast<u64*>(
          hwrite + (size_t)(gb * 32 + prow) * Hh + gj * 32 + pcq * 4);
      __hip_atomic_store(dst, pk, __ATOMIC_RELAXED, __HIP_MEMORY_SCOPE_AGENT);
    }
    __syncthreads();  // vmcnt(0) drained per wave before barrier => stores complete
    if (tid == 0) {
      __hip_atomic_store(myflag, s, __ATOMIC_RELAXED, __HIP_MEMORY_SCOPE_AGENT);
    }
  }
}

__global__ void out_dense(const __hip_bfloat16* __restrict__ hT,
                          const float* __restrict__ Wd,
                          const float* __restrict__ bd,
                          float* __restrict__ out)
{
  __shared__ float hrow[Hh];
  int b = blockIdx.x;
  int o = threadIdx.x;
  if (o < Hh / 4) {  // 128 threads x 8B
    u64 v = __hip_atomic_load(
        reinterpret_cast<const u64*>(hT + (size_t)b * Hh) + o,
        __ATOMIC_RELAXED, __HIP_MEMORY_SCOPE_AGENT);
    union { u64 u; unsigned short us[4]; } pk; pk.u = v;
#pragma unroll
    for (int q = 0; q < 4; ++q) hrow[o * 4 + q] = bf2f(pk.us[q]);
  }
  __syncthreads();
  float acc = bd[o];
  for (int k = 0; k < Hh; ++k)
    acc = fmaf(hrow[k], Wd[(size_t)k * Oo + o], acc);
  out[(size_t)b * Oo + o] = acc;
}

extern "C" void kernel_launch(void* const* d_in, const int* in_sizes, int n_in,
                              void* d_out, int out_size, void* d_ws, size_t ws_size,
                              hipStream_t stream) {
  (void)in_sizes; (void)n_in; (void)out_size; (void)ws_size;
  const float* X  = (const float*)d_in[0];
  const float* Wi = (const float*)d_in[1];
  const float* Wh = (const float*)d_in[2];
  const float* b  = (const float*)d_in[3];
  const float* Wd = (const float*)d_in[4];
  const float* bd = (const float*)d_in[5];
  float* out = (float*)d_out;

  char* ws = (char*)d_ws;
  int* flags = (int*)(ws + FLAGS_OFF);
  __hip_bfloat16* hbuf = (__hip_bfloat16*)(ws + HBUF_OFF);

  // zero flags + h(0) every launch (graph-replay deterministic)
  hipMemsetAsync(d_ws, 0, WS_ZERO_BYTES, stream);
  lstm_seq<<<NWG, BLOCK, 0, stream>>>(X, Wi, Wh, b, hbuf, flags);
  out_dense<<<Bb, Oo, 0, stream>>>(hbuf, Wd, bd, out);
}

// Round 4
// 2751.495 us; speedup vs baseline: 4.7520x; 2.8869x over previous
//
#include <hip/hip_runtime.h>
#include <hip/hip_bf16.h>

// Problem sizes
#define Bb 128
#define Tt 1024
#define Dd 256
#define Hh 512
#define G4 2048
#define Oo 256

#define NBG 8       // batch groups (16 rows each), ideally one per XCD
#define WPB 8       // workgroups per batch group
#define NWG 64
#define BLOCK 512   // 8 waves

#define SPIN_CAP (1u << 22)   // escape valve: never hang the harness

typedef __attribute__((ext_vector_type(8)))  short  short8;
typedef __attribute__((ext_vector_type(4)))  float  f32x4;
typedef unsigned long long u64;

// ws layout: [xcc_post: 64 ints][cnt: 8 x 128B @256][hbuf: 2*128*512 bf16 @4096]
#define XCC_OFF  0
#define CNT_OFF  256
#define HBUF_OFF 4096
#define WS_ZERO_BYTES (4096 + Bb*Hh*2)   // xcc + counters + hbuf half 0

__device__ __forceinline__ short f2bf(float f) {
  __hip_bfloat16 h = __float2bfloat16(f);
  return *reinterpret_cast<short*>(&h);
}
__device__ __forceinline__ float sigm(float x) {
  return __builtin_amdgcn_rcpf(1.f + __expf(-x));
}
__device__ __forceinline__ float tanh_(float x) {
  return fmaf(2.f, __builtin_amdgcn_rcpf(1.f + __expf(-2.f * x)), -1.f);
}

__global__ __launch_bounds__(BLOCK, 2) void lstm_seq(
    const float* __restrict__ X, const float* __restrict__ Wi,
    const float* __restrict__ Wh, const float* __restrict__ bias,
    char* hbuf, int* cnts, int* xcc_post)
{
  __shared__ char sH[16 * 1024];           // 16 rows x 512 bf16, XOR-swizzled
  __shared__ char sX[16 * 512];            // 16 rows x 256 bf16, XOR-swizzled
  __shared__ float sY[8][16][36];          // per-wave y staging, pad +4 (bank-safe)
  __shared__ unsigned short hstage[16][72];// wg's h slice (16 rows x 64 cols), padded
  __shared__ int sFast;

  const int tid  = threadIdx.x;
  const int w    = tid >> 6;      // wave 0..7
  const int lane = tid & 63;

  const int bg  = blockIdx.x & 7;  // batch group == target XCD (round-robin heur.)
  const int gjw = blockIdx.x >> 3; // col-group within bg: h-cols [gjw*64, +64)

  // ---- XCD co-residency check (one-time). Fast mode only if all 8 wgs of
  // this bg share an XCC; otherwise agent-scope fallback (always correct).
  int myxcc;
  asm volatile("s_getreg_b32 %0, hwreg(HW_REG_XCC_ID)" : "=s"(myxcc));
  if (tid == 0) {
    __hip_atomic_store(&xcc_post[blockIdx.x], myxcc + 1,
                       __ATOMIC_RELAXED, __HIP_MEMORY_SCOPE_AGENT);
    int ok = 1;
    for (int p = 0; p < WPB; ++p) {
      int v; unsigned spin = 0;
      do {
        v = __hip_atomic_load(&xcc_post[bg + p * NBG],
                              __ATOMIC_RELAXED, __HIP_MEMORY_SCOPE_AGENT);
      } while (v == 0 && ++spin < SPIN_CAP);
      ok &= (v == myxcc + 1);
    }
    sFast = ok;
  }
  __syncthreads();
  const bool fast = (sFast != 0);
  int* cnt = cnts + bg * 32;  // 128B apart

  // ---- Persistent weight B-fragments: wf[nt][kk], nt0 = gates i,f ; nt1 = g,o
  // B lane map (16x16x32): col = lane&15, k = kk*32 + (lane>>4)*8 + i
  short8 wf[2][24];
  float bv[2];
#pragma unroll
  for (int nt = 0; nt < 2; ++nt) {
    int c = nt * 16 + (lane & 15);
    int gate = c >> 3, jj = c & 7;
    int colg = gate * Hh + gjw * 64 + w * 8 + jj;
    bv[nt] = bias[colg];
#pragma unroll
    for (int kk = 0; kk < 24; ++kk) {
      short8 f;
#pragma unroll
      for (int i = 0; i < 8; ++i) {
        int k = kk * 32 + (lane >> 4) * 8 + i;
        float v = (k < Hh) ? Wh[(size_t)k * G4 + colg]
                           : Wi[(size_t)(k - Hh) * G4 + colg];
        f[i] = f2bf(v);
      }
      wf[nt][kk] = f;
    }
  }

  // epilogue lane mapping: lane owns rows (er0, er0+8) x h-col ejj
  const int ejj = lane & 7;
  const int er0 = lane >> 3;        // 0..7
  float cpr[2] = {0.f, 0.f};

  const int arow = lane & 15;       // MFMA A row
  const int kgrp = lane >> 4;       // 0..3
  const int aswz = (arow & 7) << 4;

  for (int s = 1; s <= Tt; ++s) {
    const char* hread  = hbuf + (size_t)((s - 1) & 1) * (Bb * Hh * 2);
    char*       hwrite = hbuf + (size_t)(s & 1) * (Bb * Hh * 2);

    // ---- stage x_t (read-only input, plain cached loads): 16 rows x 256 f32
    {
      int row = tid >> 5, seg = tid & 31;
      const float* xp = X + ((size_t)(bg * 16 + row) * Tt + (s - 1)) * Dd + seg * 8;
      f32x4 x0 = *reinterpret_cast<const f32x4*>(xp);
      f32x4 x1 = *reinterpret_cast<const f32x4*>(xp + 4);
      short8 xb;
      xb[0] = f2bf(x0[0]); xb[1] = f2bf(x0[1]); xb[2] = f2bf(x0[2]); xb[3] = f2bf(x0[3]);
      xb[4] = f2bf(x1[0]); xb[5] = f2bf(x1[1]); xb[6] = f2bf(x1[2]); xb[7] = f2bf(x1[3]);
      *reinterpret_cast<short8*>(sX + row * 512 + ((seg * 16) ^ ((row & 7) << 4))) = xb;
    }

    // ---- wait for all 8 producers of this bg to finish step s-1
    if (s > 1 && tid == 0) {
      const int tgt = WPB * (s - 1);
      unsigned spin = 0;
      if (fast) {
        // non-idempotent RMW: executes at XCD L2 (same point as producer +1s);
        // cannot be canonicalized into an L1-cacheable load.
        while ((__hip_atomic_fetch_add(cnt, 0x10000, __ATOMIC_RELAXED,
                                       __HIP_MEMORY_SCOPE_WORKGROUP) & 0xFFFF) < tgt
               && ++spin < SPIN_CAP) {
          __builtin_amdgcn_s_sleep(1);
        }
      } else {
        while (__hip_atomic_load(cnt, __ATOMIC_RELAXED,
                                 __HIP_MEMORY_SCOPE_AGENT) < tgt
               && ++spin < SPIN_CAP) {
          __builtin_amdgcn_s_sleep(1);
        }
      }
    }
    __syncthreads();

    // ---- load h(s-1): 16 rows x 512 bf16 = 16KB
    if (fast) {
      asm volatile("buffer_inv sc0" ::: "memory");  // L1-only invalidate; hits XCD L2
#pragma unroll
      for (int q = 0; q < 2; ++q) {
        int c = tid + q * 512, row = c >> 6, off = c & 63;
        f32x4 v = *reinterpret_cast<const f32x4*>(
            hread + (size_t)(bg * 16 + row) * 1024 + off * 16);
        *reinterpret_cast<f32x4*>(sH + row * 1024 + ((off * 16) ^ ((row & 7) << 4))) = v;
      }
    } else {
#pragma unroll
      for (int q = 0; q < 2; ++q) {
        int c = tid + q * 512, row = c >> 6, off = c & 63;
        const u64* src = reinterpret_cast<const u64*>(
            hread + (size_t)(bg * 16 + row) * 1024 + off * 16);
        u64 lo = __hip_atomic_load(src,     __ATOMIC_RELAXED, __HIP_MEMORY_SCOPE_AGENT);
        u64 hi = __hip_atomic_load(src + 1, __ATOMIC_RELAXED, __HIP_MEMORY_SCOPE_AGENT);
        union { u64 u[2]; f32x4 v; } cv; cv.u[0] = lo; cv.u[1] = hi;
        *reinterpret_cast<f32x4*>(sH + row * 1024 + ((off * 16) ^ ((row & 7) << 4))) = cv.v;
      }
    }
    __syncthreads();

    // ---- MFMA: 24 k-steps x 2 n-tiles of 16x16x32
    f32x4 acc0, acc1;
#pragma unroll
    for (int m = 0; m < 4; ++m) { acc0[m] = bv[0]; acc1[m] = bv[1]; }
#pragma unroll
    for (int kk = 0; kk < 16; ++kk) {   // h part, k = 0..511
      short8 a = *reinterpret_cast<const short8*>(
          sH + arow * 1024 + ((kk * 64 + kgrp * 16) ^ aswz));
      acc0 = __builtin_amdgcn_mfma_f32_16x16x32_bf16(a, wf[0][kk], acc0, 0, 0, 0);
      acc1 = __builtin_amdgcn_mfma_f32_16x16x32_bf16(a, wf[1][kk], acc1, 0, 0, 0);
    }
#pragma unroll
    for (int kk = 0; kk < 8; ++kk) {    // x part, k = 512..767
      short8 a = *reinterpret_cast<const short8*>(
          sX + arow * 512 + ((kk * 64 + kgrp * 16) ^ aswz));
      acc0 = __builtin_amdgcn_mfma_f32_16x16x32_bf16(a, wf[0][16 + kk], acc0, 0, 0, 0);
      acc1 = __builtin_amdgcn_mfma_f32_16x16x32_bf16(a, wf[1][16 + kk], acc1, 0, 0, 0);
    }

    // ---- epilogue (wave-local sY; C/D: col=lane&15, row=(lane>>4)*4+m)
    float* sYw = &sY[w][0][0];
#pragma unroll
    for (int m = 0; m < 4; ++m) {
      int row = kgrp * 4 + m;
      sYw[row * 36 + (lane & 15)]      = acc0[m];
      sYw[row * 36 + 16 + (lane & 15)] = acc1[m];
    }
#pragma unroll
    for (int q = 0; q < 2; ++q) {
      int r = er0 + q * 8;
      float yi = sYw[r * 36 + ejj];
      float yf = sYw[r * 36 + 8 + ejj];
      float yg = sYw[r * 36 + 16 + ejj];
      float yo = sYw[r * 36 + 24 + ejj];
      float ig = sigm(yi), fg = sigm(yf), gg = tanh_(yg), og = sigm(yo);
      float c = fg * cpr[q] + ig * gg;
      cpr[q] = c;
      float hh = og * tanh_(c);
      __hip_bfloat16 hb = __float2bfloat16(hh);
      hstage[r][w * 8 + ejj] = *reinterpret_cast<unsigned short*>(&hb);
    }
    __syncthreads();

    // ---- store h slice: 16 rows x 64 cols x 2B = 2KB (threads 0..127, 16B each)
    if (tid < 128) {
      int row = tid >> 3, colq = tid & 7;
      f32x4 v = *reinterpret_cast<const f32x4*>(
          reinterpret_cast<const char*>(&hstage[0][0]) + row * 144 + colq * 16);
      char* dst = hwrite + ((size_t)(bg * 16 + row) * Hh + gjw * 64 + colq * 8) * 2;
      if (fast) {
        *reinterpret_cast<f32x4*>(dst) = v;   // write-through L1 -> shared XCD L2
      } else {
        union { f32x4 v; u64 u[2]; } cv; cv.v = v;
        u64* d64 = reinterpret_cast<u64*>(dst);
        __hip_atomic_store(d64,     cv.u[0], __ATOMIC_RELAXED, __HIP_MEMORY_SCOPE_AGENT);
        __hip_atomic_store(d64 + 1, cv.u[1], __ATOMIC_RELAXED, __HIP_MEMORY_SCOPE_AGENT);
      }
    }
    __syncthreads();  // all waves drain vmcnt before barrier => stores at L2/L3

    if (tid == 0) {
      if (fast) (void)__hip_atomic_fetch_add(cnt, 1, __ATOMIC_RELAXED,
                                             __HIP_MEMORY_SCOPE_WORKGROUP);
      else      (void)__hip_atomic_fetch_add(cnt, 1, __ATOMIC_RELAXED,
                                             __HIP_MEMORY_SCOPE_AGENT);
    }
  }
}

__global__ void out_dense(const __hip_bfloat16* __restrict__ hT,
                          const float* __restrict__ Wd,
                          const float* __restrict__ bd,
                          float* __restrict__ out)
{
  // lstm_seq's kernel-completion release writes dirty L2 back; plain loads ok.
  __shared__ float hrow[Hh];
  int b = blockIdx.x;
  int o = threadIdx.x;
  for (int k = o; k < Hh; k += Oo)
    hrow[k] = __bfloat162float(hT[(size_t)b * Hh + k]);
  __syncthreads();
  float acc = bd[o];
  for (int k = 0; k < Hh; ++k)
    acc = fmaf(hrow[k], Wd[(size_t)k * Oo + o], acc);
  out[(size_t)b * Oo + o] = acc;
}

extern "C" void kernel_launch(void* const* d_in, const int* in_sizes, int n_in,
                              void* d_out, int out_size, void* d_ws, size_t ws_size,
                              hipStream_t stream) {
  (void)in_sizes; (void)n_in; (void)out_size; (void)ws_size;
  const float* X  = (const float*)d_in[0];
  const float* Wi = (const float*)d_in[1];
  const float* Wh = (const float*)d_in[2];
  const float* b  = (const float*)d_in[3];
  const float* Wd = (const float*)d_in[4];
  const float* bd = (const float*)d_in[5];
  float* out = (float*)d_out;

  char* ws = (char*)d_ws;
  int* xcc_post = (int*)(ws + XCC_OFF);
  int* cnts     = (int*)(ws + CNT_OFF);
  char* hbuf    = ws + HBUF_OFF;

  // zero xcc slots, counters, and h(0) every launch (graph-replay deterministic)
  hipMemsetAsync(d_ws, 0, WS_ZERO_BYTES, stream);
  lstm_seq<<<NWG, BLOCK, 0, stream>>>(X, Wi, Wh, b, hbuf, cnts, xcc_post);
  out_dense<<<Bb, Oo, 0, stream>>>((const __hip_bfloat16*)hbuf, Wd, bd, out);
}